// Round 2
// baseline (5660.080 us; speedup 1.0000x reference)
//
#include <hip/hip_runtime.h>
#include <stdint.h>
#include <string.h>

// Problem constants
#define NB   131072   // batch
#define DIN  128
#define HD   256      // hidden
#define VT   6        // total vocab
#define TS   6        // steps
// Tiling
#define BM   64       // rows per block
#define KB   8        // k-tile rows
#define HPAD 260      // h row stride (260*4B: 16B aligned, bank-spread)

struct Keys { uint32_t a[6]; uint32_t b[6]; };

// ---- JAX threefry2x32 (20 rounds), bit-exact ----
__host__ __device__ inline void tf2x32(uint32_t k0, uint32_t k1,
                                       uint32_t c0, uint32_t c1,
                                       uint32_t& o0, uint32_t& o1) {
  uint32_t ks2 = k0 ^ k1 ^ 0x1BD11BDAu;
  uint32_t x0 = c0 + k0, x1 = c1 + k1;
#define TFR(d) { x0 += x1; x1 = (x1 << (d)) | (x1 >> (32 - (d))); x1 ^= x0; }
  TFR(13) TFR(15) TFR(26) TFR(6)
  x0 += k1;  x1 += ks2 + 1u;
  TFR(17) TFR(29) TFR(16) TFR(24)
  x0 += ks2; x1 += k0 + 2u;
  TFR(13) TFR(15) TFR(26) TFR(6)
  x0 += k0;  x1 += k1 + 3u;
  TFR(17) TFR(29) TFR(16) TFR(24)
  x0 += k1;  x1 += ks2 + 4u;
  TFR(13) TFR(15) TFR(26) TFR(6)
  x0 += ks2; x1 += k0 + 5u;
#undef TFR
  o0 = x0; o1 = x1;
}

// ---- Kernel A: pre_g[c][j] = xin_c @ Wg_top[:,j]  (no bias; bias added at GEMM end)
// codes: 0..5 = W_embed[c]+b_embed, 6 = b_embed (stopped), 7 = start_embed
__global__ void pre_kernel(const float* __restrict__ W_embed,
                           const float* __restrict__ b_embed,
                           const float* __restrict__ start_embed,
                           const float* __restrict__ W_z,
                           const float* __restrict__ W_r,
                           const float* __restrict__ W_h,
                           float* __restrict__ pre /* [3][8][256] */) {
  __shared__ float xin[HD];
  const int c = blockIdx.x & 7;
  const int g = blockIdx.x >> 3;   // 0..2
  const int j = threadIdx.x;       // 0..255
  float v;
  if (c < 6)       v = W_embed[c * HD + j] + b_embed[j];
  else if (c == 6) v = b_embed[j];
  else             v = start_embed[j];
  xin[j] = v;
  __syncthreads();
  const float* Wg = (g == 0) ? W_z : (g == 1) ? W_r : W_h;  // top half: rows 0..255
  float acc = 0.f;
  for (int k = 0; k < HD; ++k) acc += xin[k] * Wg[k * HD + j];
  pre[(g * 8 + c) * HD + j] = acc;
}

// ---- GEMM over K (A in LDS, W streamed global->LDS tile with register prefetch)
__device__ __forceinline__ void gemm_k(const float* __restrict__ Wg, int K,
                                       const float* __restrict__ a_base,
                                       float* __restrict__ wt,
                                       int tid, int ty4, int tx4,
                                       float4 acc[4][4]) {
  const int f0r = tid >> 6;               // 0..3
  const int f1r = f0r + 4;                // 4..7
  const int fc  = (tid & 63) * 4;         // col 0..252
  float4 p0 = *(const float4*)&Wg[(size_t)f0r * HD + fc];
  float4 p1 = *(const float4*)&Wg[(size_t)f1r * HD + fc];
  const int NT = K / KB;
  for (int kt = 0; kt < NT; ++kt) {
    __syncthreads();                       // previous tile's readers done
    *(float4*)&wt[f0r * HD + fc] = p0;
    *(float4*)&wt[f1r * HD + fc] = p1;
    __syncthreads();                       // tile visible
    if (kt + 1 < NT) {                     // prefetch next tile; overlaps compute below
      p0 = *(const float4*)&Wg[((size_t)(kt + 1) * KB + f0r) * HD + fc];
      p1 = *(const float4*)&Wg[((size_t)(kt + 1) * KB + f1r) * HD + fc];
    }
    const float* a = a_base + kt * KB;
#pragma unroll
    for (int kk = 0; kk < KB; ++kk) {
      float a0 = a[(ty4 + 0) * HPAD + kk];
      float a1 = a[(ty4 + 1) * HPAD + kk];
      float a2 = a[(ty4 + 2) * HPAD + kk];
      float a3 = a[(ty4 + 3) * HPAD + kk];
#pragma unroll
      for (int i = 0; i < 4; ++i) {
        float4 w = *(const float4*)&wt[kk * HD + tx4 + 64 * i];
        acc[0][i].x += a0 * w.x; acc[0][i].y += a0 * w.y; acc[0][i].z += a0 * w.z; acc[0][i].w += a0 * w.w;
        acc[1][i].x += a1 * w.x; acc[1][i].y += a1 * w.y; acc[1][i].z += a1 * w.z; acc[1][i].w += a1 * w.w;
        acc[2][i].x += a2 * w.x; acc[2][i].y += a2 * w.y; acc[2][i].z += a2 * w.z; acc[2][i].w += a2 * w.w;
        acc[3][i].x += a3 * w.x; acc[3][i].y += a3 * w.y; acc[3][i].z += a3 * w.z; acc[3][i].w += a3 * w.w;
      }
    }
  }
}

__device__ __forceinline__ float sigf(float v) { return 1.0f / (1.0f + expf(-v)); }

// ---- Kernel B: persistent per-row-block rollout
__launch_bounds__(256, 2)
__global__ void main_kernel(const float* __restrict__ x,
                            const float* __restrict__ W_enc,
                            const float* __restrict__ b_enc,
                            const float* __restrict__ W_z, const float* __restrict__ b_z,
                            const float* __restrict__ W_r, const float* __restrict__ b_r,
                            const float* __restrict__ W_h, const float* __restrict__ b_h,
                            const float* __restrict__ W_out, const float* __restrict__ b_out,
                            const float* __restrict__ pre,
                            float* __restrict__ out, Keys keys) {
  __shared__ __align__(16) float h_lds[BM * HPAD];   // 66560 B
  __shared__ __align__(16) float wt[KB * HD];        //  8192 B
  __shared__ __align__(16) float wout[HD * VT];      //  6144 B
  __shared__ unsigned state[BM];                     // code|stopped<<3|len<<4
  __shared__ float tlp[BM];

  const int tid = threadIdx.x;
  const int tx4 = (tid & 15) * 4;
  const int ty4 = (tid >> 4) * 4;
  const int b0  = blockIdx.x * BM;

  // stage W_out; init per-row state
  for (int idx = tid; idx < HD * VT; idx += 256) wout[idx] = W_out[idx];
  if (tid < BM) { state[tid] = 7u; tlp[tid] = 0.f; }

  // stage x tile into h_lds cols [0,128)
#pragma unroll
  for (int rr = 0; rr < 8; ++rr) {
    int f = tid + rr * 256;                 // 2048 float4s
    int row = f >> 5, c4 = (f & 31) * 4;
    float4 v = *(const float4*)&x[(size_t)(b0 + row) * DIN + c4];
    *(float4*)&h_lds[row * HPAD + c4] = v;
  }

  float4 acc[4][4], zz[4][4], hold[4][4];

  // ---- encoder: h0 = x @ W_enc + b_enc ----
#pragma unroll
  for (int mm = 0; mm < 4; ++mm)
#pragma unroll
    for (int i = 0; i < 4; ++i) acc[mm][i] = make_float4(0.f, 0.f, 0.f, 0.f);
  gemm_k(W_enc, DIN, h_lds, wt, tid, ty4, tx4, acc);
  __syncthreads();  // all A-reads of x done before overwriting h
#pragma unroll
  for (int i = 0; i < 4; ++i) {
    float4 bb = *(const float4*)&b_enc[tx4 + 64 * i];
#pragma unroll
    for (int mm = 0; mm < 4; ++mm) {
      float4 o = acc[mm][i];
      o.x += bb.x; o.y += bb.y; o.z += bb.z; o.w += bb.w;
      *(float4*)&h_lds[(ty4 + mm) * HPAD + tx4 + 64 * i] = o;
    }
  }
  // (next gemm_k's first barrier publishes h)

  for (int t = 0; t < TS; ++t) {
    // ---- z gate ----
#pragma unroll
    for (int mm = 0; mm < 4; ++mm) {
      const float* p = pre + 0 * 8 * HD + (state[ty4 + mm] & 7u) * HD;
#pragma unroll
      for (int i = 0; i < 4; ++i) acc[mm][i] = *(const float4*)&p[tx4 + 64 * i];
    }
    gemm_k(W_z + 256 * HD, HD, h_lds, wt, tid, ty4, tx4, acc);
#pragma unroll
    for (int i = 0; i < 4; ++i) {
      float4 b4 = *(const float4*)&b_z[tx4 + 64 * i];
#pragma unroll
      for (int mm = 0; mm < 4; ++mm) {
        zz[mm][i].x = sigf(acc[mm][i].x + b4.x);
        zz[mm][i].y = sigf(acc[mm][i].y + b4.y);
        zz[mm][i].z = sigf(acc[mm][i].z + b4.z);
        zz[mm][i].w = sigf(acc[mm][i].w + b4.w);
      }
    }
    // ---- r gate ----
#pragma unroll
    for (int mm = 0; mm < 4; ++mm) {
      const float* p = pre + 1 * 8 * HD + (state[ty4 + mm] & 7u) * HD;
#pragma unroll
      for (int i = 0; i < 4; ++i) acc[mm][i] = *(const float4*)&p[tx4 + 64 * i];
    }
    gemm_k(W_r + 256 * HD, HD, h_lds, wt, tid, ty4, tx4, acc);
    __syncthreads();  // all A-reads of h done; safe to overwrite with r*h
#pragma unroll
    for (int i = 0; i < 4; ++i) {
      float4 b4 = *(const float4*)&b_r[tx4 + 64 * i];
#pragma unroll
      for (int mm = 0; mm < 4; ++mm) {
        float* hp = &h_lds[(ty4 + mm) * HPAD + tx4 + 64 * i];
        float4 hv = *(float4*)hp;
        hold[mm][i] = hv;
        float4 hr;
        hr.x = sigf(acc[mm][i].x + b4.x) * hv.x;
        hr.y = sigf(acc[mm][i].y + b4.y) * hv.y;
        hr.z = sigf(acc[mm][i].z + b4.z) * hv.z;
        hr.w = sigf(acc[mm][i].w + b4.w) * hv.w;
        *(float4*)hp = hr;
      }
    }
    // ---- candidate gate ----
#pragma unroll
    for (int mm = 0; mm < 4; ++mm) {
      const float* p = pre + 2 * 8 * HD + (state[ty4 + mm] & 7u) * HD;
#pragma unroll
      for (int i = 0; i < 4; ++i) acc[mm][i] = *(const float4*)&p[tx4 + 64 * i];
    }
    gemm_k(W_h + 256 * HD, HD, h_lds, wt, tid, ty4, tx4, acc);
    __syncthreads();  // all A-reads of hr done; safe to overwrite with h_new
#pragma unroll
    for (int i = 0; i < 4; ++i) {
      float4 b4 = *(const float4*)&b_h[tx4 + 64 * i];
#pragma unroll
      for (int mm = 0; mm < 4; ++mm) {
        float4 ht;
        ht.x = tanhf(acc[mm][i].x + b4.x);
        ht.y = tanhf(acc[mm][i].y + b4.y);
        ht.z = tanhf(acc[mm][i].z + b4.z);
        ht.w = tanhf(acc[mm][i].w + b4.w);
        float4 z = zz[mm][i], ho = hold[mm][i], hn;
        hn.x = (1.0f - z.x) * ho.x + z.x * ht.x;
        hn.y = (1.0f - z.y) * ho.y + z.y * ht.y;
        hn.z = (1.0f - z.z) * ho.z + z.z * ht.z;
        hn.w = (1.0f - z.w) * ho.w + z.w * ht.w;
        *(float4*)&h_lds[(ty4 + mm) * HPAD + tx4 + 64 * i] = hn;
      }
    }
    __syncthreads();  // h_new visible for logits

    // ---- logits + sampling: one thread per row (wave 0) ----
    if (tid < BM) {
      const int m = tid;
      const int row = b0 + m;
      unsigned st = state[m];
      if (!(st & 8u)) {
        float l[VT] = {0.f, 0.f, 0.f, 0.f, 0.f, 0.f};
        for (int k = 0; k < HD; ++k) {
          float hv = h_lds[m * HPAD + k];
#pragma unroll
          for (int v = 0; v < VT; ++v) l[v] += hv * wout[k * VT + v];
        }
#pragma unroll
        for (int v = 0; v < VT; ++v) l[v] += b_out[v];

        // gumbel-argmax, bit-matching jax.random.categorical with
        // jax_threefry_partitionable=True (default since JAX 0.4.30):
        // element j of (B,VT) uses 64-bit counter (hi=0, lo=j); bits = o0 ^ o1.
        const uint32_t k0 = keys.a[t], k1 = keys.b[t];
        float best = 0.f; int tok = 0;
#pragma unroll
        for (int v = 0; v < VT; ++v) {
          uint32_t j = (uint32_t)row * 6u + (uint32_t)v;
          uint32_t o0, o1;
          tf2x32(k0, k1, 0u, j, o0, o1);
          uint32_t bits = o0 ^ o1;
          float f = __uint_as_float((bits >> 9) | 0x3f800000u) - 1.0f;
          float u = (f > 0.f) ? f : 1.175494350822288e-38f;
          float lg1 = (float)log((double)u);     // ~correctly-rounded logf
          float lg2 = (float)log((double)(-lg1));
          float val = l[v] + (-lg2);
          if (v == 0 || val > best) { best = val; tok = v; }  // first-max
        }
        // log_softmax value at tok
        float lmax = l[0];
#pragma unroll
        for (int v = 1; v < VT; ++v) lmax = fmaxf(lmax, l[v]);
        float s = 0.f;
#pragma unroll
        for (int v = 0; v < VT; ++v) s += expf(l[v] - lmax);
        float lp = (l[tok] - lmax) - logf(s);
        tlp[m] += lp;

        const bool is_stop = (tok == VT - 1);
        unsigned len = ((st >> 4) & 7u) + (is_stop ? 0u : 1u);
#pragma unroll
        for (int v = 0; v < VT; ++v)
          out[(size_t)row * (TS * VT) + t * VT + v] = (v == tok) ? 1.0f : 0.0f;
        state[m] = (unsigned)tok | (is_stop ? 8u : 0u) | (len << 4);
      } else {
#pragma unroll
        for (int v = 0; v < VT; ++v)
          out[(size_t)row * (TS * VT) + t * VT + v] = 0.0f;
        state[m] = 6u | 8u | (st & 0x70u);  // prev_embed = b_embed; keep len
      }
    }
    __syncthreads();  // state/tlp visible for next step's pre-table init
  }

  if (tid < BM) {
    const int row = b0 + tid;
    out[(size_t)NB * (TS * VT) + row]      = tlp[tid];
    out[(size_t)NB * (TS * VT) + NB + row] = (float)((state[tid] >> 4) & 7u);
  }
}

extern "C" void kernel_launch(void* const* d_in, const int* in_sizes, int n_in,
                              void* d_out, int out_size, void* d_ws, size_t ws_size,
                              hipStream_t stream) {
  (void)in_sizes; (void)n_in; (void)out_size; (void)ws_size;
  const float* x          = (const float*)d_in[0];
  const float* W_enc      = (const float*)d_in[1];
  const float* b_enc      = (const float*)d_in[2];
  const float* W_embed    = (const float*)d_in[3];
  const float* b_embed    = (const float*)d_in[4];
  const float* W_z        = (const float*)d_in[5];
  const float* b_z        = (const float*)d_in[6];
  const float* W_r        = (const float*)d_in[7];
  const float* b_r        = (const float*)d_in[8];
  const float* W_h        = (const float*)d_in[9];
  const float* b_h        = (const float*)d_in[10];
  const float* W_out      = (const float*)d_in[11];
  const float* b_out      = (const float*)d_in[12];
  const float* start_embed= (const float*)d_in[13];
  float* out = (float*)d_out;
  float* pre = (float*)d_ws;   // 3*8*256 floats = 24 KiB

  pre_kernel<<<24, 256, 0, stream>>>(W_embed, b_embed, start_embed, W_z, W_r, W_h, pre);

  // keys = jax.random.split(jax.random.key(42), 6) with threefry_partitionable=True:
  // key[t] = threefry2x32(k0=0, k1=42, c0=0, c1=t) -> (o0, o1)
  Keys K;
  for (int t = 0; t < 6; ++t) {
    uint32_t o0, o1;
    tf2x32(0u, 42u, 0u, (uint32_t)t, o0, o1);
    K.a[t] = o0; K.b[t] = o1;
  }

  main_kernel<<<NB / BM, 256, 0, stream>>>(x, W_enc, b_enc, W_z, b_z, W_r, b_r,
                                           W_h, b_h, W_out, b_out, pre, out, K);
}